// Round 2
// baseline (739.768 us; speedup 1.0000x reference)
//
#include <hip/hip_runtime.h>

#define N_NODES 100000

// ---------------- preprocessing: degree / CSR-by-target ----------------

__global__ void k_zero(int* __restrict__ counts) {
    int i = blockIdx.x * 256 + threadIdx.x;
    if (i < N_NODES) counts[i] = 0;
}

__global__ void k_hist(const int* __restrict__ edges, int E,
                       int* __restrict__ counts) {
    int stride = gridDim.x * blockDim.x;
    for (int e = blockIdx.x * blockDim.x + threadIdx.x; e < E; e += stride) {
        int c = edges[E + e];               // col (target)
        atomicAdd(&counts[c], 1);
    }
}

// block-level exclusive scan (512 elems/block, Hillis-Steele)
__global__ void k_scan1(const int* __restrict__ counts, int* __restrict__ offs,
                        int* __restrict__ bsum) {
    __shared__ int s[512];
    int i = blockIdx.x * 512 + threadIdx.x;
    int v = (i < N_NODES) ? counts[i] : 0;
    s[threadIdx.x] = v;
    __syncthreads();
    for (int off = 1; off < 512; off <<= 1) {
        int t = (threadIdx.x >= off) ? s[threadIdx.x - off] : 0;
        __syncthreads();
        s[threadIdx.x] += t;
        __syncthreads();
    }
    if (i < N_NODES) offs[i] = s[threadIdx.x] - v;   // exclusive partial
    if (threadIdx.x == 511) bsum[blockIdx.x] = s[511];
}

__global__ void k_scan2(const int* __restrict__ bsum, int* __restrict__ bbase,
                        int* __restrict__ offs, int nb) {
    int run = 0;
    for (int b = 0; b < nb; ++b) { bbase[b] = run; run += bsum[b]; }
    offs[N_NODES] = run;
}

__global__ void k_scan3(int* __restrict__ offs, const int* __restrict__ bbase,
                        int* __restrict__ pos, const int* __restrict__ counts,
                        float* __restrict__ dis) {
    int i = blockIdx.x * 256 + threadIdx.x;
    if (i < N_NODES) {
        int o = offs[i] + bbase[i >> 9];
        offs[i] = o;
        pos[i]  = o;
        // deg includes the self loop -> always >= 1
        dis[i] = rsqrtf((float)(counts[i] + 1));
    }
}

__global__ void k_fill(const int* __restrict__ edges, int E,
                       int* __restrict__ pos, int* __restrict__ csr) {
    int stride = gridDim.x * blockDim.x;
    for (int e = blockIdx.x * blockDim.x + threadIdx.x; e < E; e += stride) {
        int c = edges[E + e];
        int r = edges[e];
        int p = atomicAdd(&pos[c], 1);
        csr[p] = r;
    }
}

// ---------------- GEMM: h'[r] = dis[r] * (A[r] @ W) ----------------
// M=100000, K=128, N=128. 32 rows/block, K staged in chunks of 32.
// 256 threads: tx=t&31 -> 4 consecutive cols (float4), ty=t>>5 -> rows ty+8i.

__global__ __launch_bounds__(256) void k_gemm(const float* __restrict__ A,
                                              const float* __restrict__ W,
                                              const float* __restrict__ dis,
                                              float* __restrict__ out) {
    __shared__ float4 xs4[32 * 8];    // 32 rows x 32 k (as float4)
    __shared__ float4 ws4[32 * 32];   // 32 k x 128 cols (as float4)
    int t  = threadIdx.x;
    int tx = t & 31, ty = t >> 5;
    int rb = blockIdx.x * 32;
    const float4* A4 = (const float4*)A;
    const float4* W4 = (const float4*)W;
    float4 acc[4];
#pragma unroll
    for (int i = 0; i < 4; ++i) acc[i] = make_float4(0.f, 0.f, 0.f, 0.f);

    for (int kc = 0; kc < 4; ++kc) {
        // stage x tile: 32 rows x 8 float4
        {
            int r = t >> 3, c4 = t & 7;
            xs4[r * 8 + c4] = A4[(size_t)(rb + r) * 32 + kc * 8 + c4];
        }
        // stage W chunk: 32 k x 32 float4
#pragma unroll
        for (int i = 0; i < 4; ++i) {
            int idx = t + i * 256;
            int k = idx >> 5, c4 = idx & 31;
            ws4[k * 32 + c4] = W4[(size_t)(kc * 32 + k) * 32 + c4];
        }
        __syncthreads();
#pragma unroll
        for (int k0 = 0; k0 < 32; k0 += 4) {
            float4 b0 = ws4[(k0 + 0) * 32 + tx];
            float4 b1 = ws4[(k0 + 1) * 32 + tx];
            float4 b2 = ws4[(k0 + 2) * 32 + tx];
            float4 b3 = ws4[(k0 + 3) * 32 + tx];
#pragma unroll
            for (int i = 0; i < 4; ++i) {
                float4 a = xs4[(ty + 8 * i) * 8 + (k0 >> 2)];
                acc[i].x += a.x * b0.x; acc[i].y += a.x * b0.y;
                acc[i].z += a.x * b0.z; acc[i].w += a.x * b0.w;
                acc[i].x += a.y * b1.x; acc[i].y += a.y * b1.y;
                acc[i].z += a.y * b1.z; acc[i].w += a.y * b1.w;
                acc[i].x += a.z * b2.x; acc[i].y += a.z * b2.y;
                acc[i].z += a.z * b2.z; acc[i].w += a.z * b2.w;
                acc[i].x += a.w * b3.x; acc[i].y += a.w * b3.y;
                acc[i].z += a.w * b3.z; acc[i].w += a.w * b3.w;
            }
        }
        __syncthreads();
    }
    float4* O4 = (float4*)out;
#pragma unroll
    for (int i = 0; i < 4; ++i) {
        int r = rb + ty + 8 * i;
        float d = dis[r];
        float4 o = acc[i];
        o.x *= d; o.y *= d; o.z *= d; o.w *= d;
        O4[(size_t)r * 32 + tx] = o;
    }
}

// ---------------- aggregation: out[v] = relu?(dis[v]*(h'[v]+sum h'[src]) + b) ----
// one wave per node, each lane owns features (2*lane, 2*lane+1)

template <bool RELU>
__global__ __launch_bounds__(256) void k_agg(const float* __restrict__ h,
                                             const int* __restrict__ csr,
                                             const int* __restrict__ offs,
                                             const float* __restrict__ dis,
                                             const float* __restrict__ bias,
                                             float* __restrict__ out) {
    int v    = blockIdx.x * 4 + (threadIdx.x >> 6);
    int lane = threadIdx.x & 63;
    const float2* h2 = (const float2*)h;
    float2 acc = h2[(size_t)v * 64 + lane];      // self loop term (h'[v])
    int s = offs[v], e = offs[v + 1];
    for (int i = s; i < e; ++i) {
        int src = csr[i];
        float2 tt = h2[(size_t)src * 64 + lane];
        acc.x += tt.x; acc.y += tt.y;
    }
    float dv = dis[v];
    float2 bb = ((const float2*)bias)[lane];
    float2 o;
    o.x = dv * acc.x + bb.x;
    o.y = dv * acc.y + bb.y;
    if (RELU) { o.x = fmaxf(o.x, 0.f); o.y = fmaxf(o.y, 0.f); }
    ((float2*)out)[(size_t)v * 64 + lane] = o;
}

// ---------------- launch ----------------

extern "C" void kernel_launch(void* const* d_in, const int* in_sizes, int n_in,
                              void* d_out, int out_size, void* d_ws, size_t ws_size,
                              hipStream_t stream) {
    const float* x     = (const float*)d_in[0];
    const int*   edges = (const int*)d_in[1];     // harness stages integers as int32
    const float* W1    = (const float*)d_in[2];
    const float* b1    = (const float*)d_in[3];
    const float* W2    = (const float*)d_in[4];
    const float* b2    = (const float*)d_in[5];
    float* out = (float*)d_out;
    const int E = in_sizes[1] / 2;

    // workspace carve (~58.5 MB total)
    char* p = (char*)d_ws;
    auto alloc = [&](size_t bytes) -> char* {
        char* r = p;
        p += (bytes + 255) & ~(size_t)255;
        return r;
    };
    int*   counts = (int*)alloc((size_t)N_NODES * 4);
    int*   offs   = (int*)alloc((size_t)(N_NODES + 1) * 4);
    int*   pos    = (int*)alloc((size_t)N_NODES * 4);
    float* dis    = (float*)alloc((size_t)N_NODES * 4);
    int*   bsum   = (int*)alloc(256 * 4);
    int*   bbase  = (int*)alloc(256 * 4);
    int*   csr    = (int*)alloc((size_t)E * 4);
    float* hA     = (float*)alloc((size_t)N_NODES * 128 * 4);

    const int NB = (N_NODES + 511) / 512;   // 196

    k_zero<<<(N_NODES + 255) / 256, 256, 0, stream>>>(counts);
    k_hist<<<1024, 256, 0, stream>>>(edges, E, counts);
    k_scan1<<<NB, 512, 0, stream>>>(counts, offs, bsum);
    k_scan2<<<1, 1, 0, stream>>>(bsum, bbase, offs, NB);
    k_scan3<<<(N_NODES + 255) / 256, 256, 0, stream>>>(offs, bbase, pos, counts, dis);
    k_fill<<<1024, 256, 0, stream>>>(edges, E, pos, csr);

    // layer 1: h' = dis * (x @ W1) -> hA ; aggregate(+b1, relu) -> out (temp)
    k_gemm<<<N_NODES / 32, 256, 0, stream>>>(x, W1, dis, hA);
    k_agg<true><<<N_NODES / 4, 256, 0, stream>>>(hA, csr, offs, dis, b1, out);

    // layer 2: h' = dis * (out @ W2) -> hA ; aggregate(+b2) -> out (final)
    k_gemm<<<N_NODES / 32, 256, 0, stream>>>(out, W2, dis, hA);
    k_agg<false><<<N_NODES / 4, 256, 0, stream>>>(hA, csr, offs, dis, b2, out);
}

// Round 5
// 622.396 us; speedup vs baseline: 1.1886x; 1.1886x over previous
//
#include <hip/hip_runtime.h>

#define N_NODES 100000

// ---------------- preprocessing: degree / CSR-by-target ----------------

__global__ void k_zero(int* __restrict__ counts) {
    int i = blockIdx.x * 256 + threadIdx.x;
    if (i < N_NODES) counts[i] = 0;
}

__global__ void k_hist(const int* __restrict__ edges, int E,
                       int* __restrict__ counts) {
    int stride = gridDim.x * blockDim.x;
    for (int e = blockIdx.x * blockDim.x + threadIdx.x; e < E; e += stride) {
        int c = edges[E + e];               // col (target)
        atomicAdd(&counts[c], 1);
    }
}

// block-level exclusive scan (512 elems/block, Hillis-Steele)
__global__ void k_scan1(const int* __restrict__ counts, int* __restrict__ offs,
                        int* __restrict__ bsum) {
    __shared__ int s[512];
    int i = blockIdx.x * 512 + threadIdx.x;
    int v = (i < N_NODES) ? counts[i] : 0;
    s[threadIdx.x] = v;
    __syncthreads();
    for (int off = 1; off < 512; off <<= 1) {
        int t = (threadIdx.x >= off) ? s[threadIdx.x - off] : 0;
        __syncthreads();
        s[threadIdx.x] += t;
        __syncthreads();
    }
    if (i < N_NODES) offs[i] = s[threadIdx.x] - v;   // exclusive partial
    if (threadIdx.x == 511) bsum[blockIdx.x] = s[511];
}

// parallel scan of the 196 block sums (one block, LDS) — replaces the
// <<<1,1>>> serial loop that was costing O(100 us) of dependent latency
__global__ void k_scan2(const int* __restrict__ bsum, int* __restrict__ bbase,
                        int* __restrict__ offs, int nb) {
    __shared__ int s[256];
    int t = threadIdx.x;
    int v = (t < nb) ? bsum[t] : 0;
    s[t] = v;
    __syncthreads();
    for (int off = 1; off < 256; off <<= 1) {
        int tmp = (t >= off) ? s[t - off] : 0;
        __syncthreads();
        s[t] += tmp;
        __syncthreads();
    }
    if (t < nb) bbase[t] = s[t] - v;        // exclusive
    if (t == 255) offs[N_NODES] = s[255];
}

__global__ void k_scan3(int* __restrict__ offs, const int* __restrict__ bbase,
                        int* __restrict__ pos, const int* __restrict__ counts,
                        float* __restrict__ dis) {
    int i = blockIdx.x * 256 + threadIdx.x;
    if (i < N_NODES) {
        int o = offs[i] + bbase[i >> 9];
        offs[i] = o;
        pos[i]  = o;
        // deg includes the self loop -> always >= 1
        dis[i] = rsqrtf((float)(counts[i] + 1));
    }
}

__global__ void k_fill(const int* __restrict__ edges, int E,
                       int* __restrict__ pos, int* __restrict__ csr) {
    int stride = gridDim.x * blockDim.x;
    for (int e = blockIdx.x * blockDim.x + threadIdx.x; e < E; e += stride) {
        int c = edges[E + e];
        int r = edges[e];
        int p = atomicAdd(&pos[c], 1);
        csr[p] = r;
    }
}

// ---------------- GEMM: h'[r] = dis[r] * (A[r] @ W) ----------------
// M=100000, K=128, N=128. 32 rows/block, K staged in chunks of 32.
// 256 threads: tx=t&31 -> 4 consecutive cols (float4), ty=t>>5 -> rows ty+8i.

__global__ __launch_bounds__(256) void k_gemm(const float* __restrict__ A,
                                              const float* __restrict__ W,
                                              const float* __restrict__ dis,
                                              float* __restrict__ out) {
    __shared__ float4 xs4[32 * 8];    // 32 rows x 32 k (as float4)
    __shared__ float4 ws4[32 * 32];   // 32 k x 128 cols (as float4)
    int t  = threadIdx.x;
    int tx = t & 31, ty = t >> 5;
    int rb = blockIdx.x * 32;
    const float4* A4 = (const float4*)A;
    const float4* W4 = (const float4*)W;
    float4 acc[4];
#pragma unroll
    for (int i = 0; i < 4; ++i) acc[i] = make_float4(0.f, 0.f, 0.f, 0.f);

    for (int kc = 0; kc < 4; ++kc) {
        // stage x tile: 32 rows x 8 float4
        {
            int r = t >> 3, c4 = t & 7;
            xs4[r * 8 + c4] = A4[(size_t)(rb + r) * 32 + kc * 8 + c4];
        }
        // stage W chunk: 32 k x 32 float4
#pragma unroll
        for (int i = 0; i < 4; ++i) {
            int idx = t + i * 256;
            int k = idx >> 5, c4 = idx & 31;
            ws4[k * 32 + c4] = W4[(size_t)(kc * 32 + k) * 32 + c4];
        }
        __syncthreads();
#pragma unroll
        for (int k0 = 0; k0 < 32; k0 += 4) {
            float4 b0 = ws4[(k0 + 0) * 32 + tx];
            float4 b1 = ws4[(k0 + 1) * 32 + tx];
            float4 b2 = ws4[(k0 + 2) * 32 + tx];
            float4 b3 = ws4[(k0 + 3) * 32 + tx];
#pragma unroll
            for (int i = 0; i < 4; ++i) {
                float4 a = xs4[(ty + 8 * i) * 8 + (k0 >> 2)];
                acc[i].x += a.x * b0.x; acc[i].y += a.x * b0.y;
                acc[i].z += a.x * b0.z; acc[i].w += a.x * b0.w;
                acc[i].x += a.y * b1.x; acc[i].y += a.y * b1.y;
                acc[i].z += a.y * b1.z; acc[i].w += a.y * b1.w;
                acc[i].x += a.z * b2.x; acc[i].y += a.z * b2.y;
                acc[i].z += a.z * b2.z; acc[i].w += a.z * b2.w;
                acc[i].x += a.w * b3.x; acc[i].y += a.w * b3.y;
                acc[i].z += a.w * b3.z; acc[i].w += a.w * b3.w;
            }
        }
        __syncthreads();
    }
    float4* O4 = (float4*)out;
#pragma unroll
    for (int i = 0; i < 4; ++i) {
        int r = rb + ty + 8 * i;
        float d = dis[r];
        float4 o = acc[i];
        o.x *= d; o.y *= d; o.z *= d; o.w *= d;
        O4[(size_t)r * 32 + tx] = o;
    }
}

// ---------------- aggregation: out[v] = relu?(dis[v]*(h'[v]+sum h'[src]) + b) ----
// one wave per node, each lane owns features (2*lane, 2*lane+1).
// Edge loop unrolled x8: 8 independent 512B row-gathers in flight per wave
// (was 1 -> latency/MLP-bound at 34% HBM peak).

template <bool RELU>
__global__ __launch_bounds__(256) void k_agg(const float* __restrict__ h,
                                             const int* __restrict__ csr,
                                             const int* __restrict__ offs,
                                             const float* __restrict__ dis,
                                             const float* __restrict__ bias,
                                             float* __restrict__ out) {
    int v    = blockIdx.x * 4 + (threadIdx.x >> 6);
    int lane = threadIdx.x & 63;
    const float2* h2 = (const float2*)h;
    float2 a0 = h2[(size_t)v * 64 + lane];       // self loop term (h'[v])
    float2 a1 = make_float2(0.f, 0.f);
    int s = offs[v], e = offs[v + 1];
    int i = s;
    for (; i + 8 <= e; i += 8) {
        int s0 = csr[i + 0], s1 = csr[i + 1], s2 = csr[i + 2], s3 = csr[i + 3];
        int s4 = csr[i + 4], s5 = csr[i + 5], s6 = csr[i + 6], s7 = csr[i + 7];
        float2 t0 = h2[(size_t)s0 * 64 + lane];
        float2 t1 = h2[(size_t)s1 * 64 + lane];
        float2 t2 = h2[(size_t)s2 * 64 + lane];
        float2 t3 = h2[(size_t)s3 * 64 + lane];
        float2 t4 = h2[(size_t)s4 * 64 + lane];
        float2 t5 = h2[(size_t)s5 * 64 + lane];
        float2 t6 = h2[(size_t)s6 * 64 + lane];
        float2 t7 = h2[(size_t)s7 * 64 + lane];
        a0.x += t0.x; a0.y += t0.y;  a1.x += t1.x; a1.y += t1.y;
        a0.x += t2.x; a0.y += t2.y;  a1.x += t3.x; a1.y += t3.y;
        a0.x += t4.x; a0.y += t4.y;  a1.x += t5.x; a1.y += t5.y;
        a0.x += t6.x; a0.y += t6.y;  a1.x += t7.x; a1.y += t7.y;
    }
    for (; i + 2 <= e; i += 2) {
        int s0 = csr[i], s1 = csr[i + 1];
        float2 t0 = h2[(size_t)s0 * 64 + lane];
        float2 t1 = h2[(size_t)s1 * 64 + lane];
        a0.x += t0.x; a0.y += t0.y;  a1.x += t1.x; a1.y += t1.y;
    }
    if (i < e) {
        int s0 = csr[i];
        float2 t0 = h2[(size_t)s0 * 64 + lane];
        a0.x += t0.x; a0.y += t0.y;
    }
    float dv = dis[v];
    float2 bb = ((const float2*)bias)[lane];
    float2 o;
    o.x = dv * (a0.x + a1.x) + bb.x;
    o.y = dv * (a0.y + a1.y) + bb.y;
    if (RELU) { o.x = fmaxf(o.x, 0.f); o.y = fmaxf(o.y, 0.f); }
    ((float2*)out)[(size_t)v * 64 + lane] = o;
}

// ---------------- launch ----------------

extern "C" void kernel_launch(void* const* d_in, const int* in_sizes, int n_in,
                              void* d_out, int out_size, void* d_ws, size_t ws_size,
                              hipStream_t stream) {
    const float* x     = (const float*)d_in[0];
    const int*   edges = (const int*)d_in[1];     // harness stages integers as int32
    const float* W1    = (const float*)d_in[2];
    const float* b1    = (const float*)d_in[3];
    const float* W2    = (const float*)d_in[4];
    const float* b2    = (const float*)d_in[5];
    float* out = (float*)d_out;
    const int E = in_sizes[1] / 2;

    // workspace carve (~58.5 MB total)
    char* p = (char*)d_ws;
    auto alloc = [&](size_t bytes) -> char* {
        char* r = p;
        p += (bytes + 255) & ~(size_t)255;
        return r;
    };
    int*   counts = (int*)alloc((size_t)N_NODES * 4);
    int*   offs   = (int*)alloc((size_t)(N_NODES + 1) * 4);
    int*   pos    = (int*)alloc((size_t)N_NODES * 4);
    float* dis    = (float*)alloc((size_t)N_NODES * 4);
    int*   bsum   = (int*)alloc(256 * 4);
    int*   bbase  = (int*)alloc(256 * 4);
    int*   csr    = (int*)alloc((size_t)E * 4);
    float* hA     = (float*)alloc((size_t)N_NODES * 128 * 4);

    const int NB = (N_NODES + 511) / 512;   // 196

    k_zero<<<(N_NODES + 255) / 256, 256, 0, stream>>>(counts);
    k_hist<<<1024, 256, 0, stream>>>(edges, E, counts);
    k_scan1<<<NB, 512, 0, stream>>>(counts, offs, bsum);
    k_scan2<<<1, 256, 0, stream>>>(bsum, bbase, offs, NB);
    k_scan3<<<(N_NODES + 255) / 256, 256, 0, stream>>>(offs, bbase, pos, counts, dis);
    k_fill<<<1024, 256, 0, stream>>>(edges, E, pos, csr);

    // layer 1: h' = dis * (x @ W1) -> hA ; aggregate(+b1, relu) -> out (temp)
    k_gemm<<<N_NODES / 32, 256, 0, stream>>>(x, W1, dis, hA);
    k_agg<true><<<N_NODES / 4, 256, 0, stream>>>(hA, csr, offs, dis, b1, out);

    // layer 2: h' = dis * (out @ W2) -> hA ; aggregate(+b2) -> out (final)
    k_gemm<<<N_NODES / 32, 256, 0, stream>>>(out, W2, dis, hA);
    k_agg<false><<<N_NODES / 4, 256, 0, stream>>>(hA, csr, offs, dis, b2, out);
}

// Round 9
// 543.274 us; speedup vs baseline: 1.3617x; 1.1456x over previous
//
#include <hip/hip_runtime.h>

#define N_NODES 100000
#define NBUCK 196        // ceil(100000 / 512) node buckets
#define BSH 9            // 512 nodes per bucket
#define TILE 4096        // edges per binning tile
#define EPT 16           // TILE / 256 threads
#define CAP 10240        // k_csr LDS stage capacity (mean 8192, sd ~90 -> 22 sigma)

// ---------------- preprocessing: degree / offsets ----------------

__global__ void k_zero(int* __restrict__ counts) {
    int i = blockIdx.x * 256 + threadIdx.x;
    if (i < N_NODES) counts[i] = 0;
}

__global__ void k_hist(const int* __restrict__ edges, int E,
                       int* __restrict__ counts) {
    int stride = gridDim.x * blockDim.x;
    for (int e = blockIdx.x * blockDim.x + threadIdx.x; e < E; e += stride) {
        int c = edges[E + e];               // col (target)
        atomicAdd(&counts[c], 1);
    }
}

// block-level exclusive scan (512 elems/block, Hillis-Steele)
__global__ void k_scan1(const int* __restrict__ counts, int* __restrict__ offs,
                        int* __restrict__ bsum) {
    __shared__ int s[512];
    int i = blockIdx.x * 512 + threadIdx.x;
    int v = (i < N_NODES) ? counts[i] : 0;
    s[threadIdx.x] = v;
    __syncthreads();
    for (int off = 1; off < 512; off <<= 1) {
        int t = (threadIdx.x >= off) ? s[threadIdx.x - off] : 0;
        __syncthreads();
        s[threadIdx.x] += t;
        __syncthreads();
    }
    if (i < N_NODES) offs[i] = s[threadIdx.x] - v;   // exclusive partial
    if (threadIdx.x == 511) bsum[blockIdx.x] = s[511];
}

// parallel scan of the 196 block sums (one block, LDS)
__global__ void k_scan2(const int* __restrict__ bsum, int* __restrict__ bbase,
                        int* __restrict__ offs, int nb) {
    __shared__ int s[256];
    int t = threadIdx.x;
    int v = (t < nb) ? bsum[t] : 0;
    s[t] = v;
    __syncthreads();
    for (int off = 1; off < 256; off <<= 1) {
        int tmp = (t >= off) ? s[t - off] : 0;
        __syncthreads();
        s[t] += tmp;
        __syncthreads();
    }
    if (t < nb) bbase[t] = s[t] - v;        // exclusive
    if (t == 255) offs[N_NODES] = s[255];   // = E
}

__global__ void k_scan3(int* __restrict__ offs, const int* __restrict__ bbase,
                        const int* __restrict__ counts, float* __restrict__ dis,
                        int* __restrict__ gtail) {
    int i = blockIdx.x * 256 + threadIdx.x;
    if (i < N_NODES) {
        int o = offs[i] + bbase[i >> 9];
        offs[i] = o;
        dis[i] = rsqrtf((float)(counts[i] + 1));   // +1: self loop
        if ((i & 511) == 0) gtail[i >> BSH] = o;   // bucket write cursor init
    }
}

// ---------------- CSR build, write-coalesced ----------------
// Phase A: tile-sort 4096 edges/block into 196 coarse buckets in LDS, then
// append bucket-runs (~84B contiguous) to global bin[] regions. Entry packed
// as (row<<9 | col&511), 4B. Replaces the old scatter k_fill whose 4B random
// stores amplified to ~62B HBM write each (WRITE_SIZE 106MB for 6.4MB data).

__global__ __launch_bounds__(256) void k_binA(const int* __restrict__ edges, int E,
                                              int* __restrict__ gtail,
                                              unsigned int* __restrict__ bin) {
    __shared__ int cnt[NBUCK];
    __shared__ int excl[NBUCK + 1];
    __shared__ int cur[NBUCK];
    __shared__ int gb[NBUCK];
    __shared__ int s[256];
    __shared__ unsigned int reorder[TILE];

    int t = threadIdx.x;
    int base = blockIdx.x * TILE;
    for (int b = t; b < NBUCK; b += 256) cnt[b] = 0;
    __syncthreads();

    int n = E - base;
    if (n > TILE) n = TILE;

    unsigned int pk[EPT];
    int bk[EPT];
#pragma unroll
    for (int i = 0; i < EPT; ++i) {
        int idx = i * 256 + t;
        if (idx < n) {
            int e = base + idx;
            int r = edges[e];
            int c = edges[E + e];
            int b = c >> BSH;
            pk[i] = ((unsigned)r << BSH) | (unsigned)(c & 511);
            bk[i] = b;
            atomicAdd(&cnt[b], 1);
        } else {
            bk[i] = -1;
            pk[i] = 0;
        }
    }
    __syncthreads();

    // exclusive scan of cnt[0..195] (Hillis-Steele over 256)
    int v = (t < NBUCK) ? cnt[t] : 0;
    s[t] = v;
    __syncthreads();
    for (int off = 1; off < 256; off <<= 1) {
        int tmp = (t >= off) ? s[t - off] : 0;
        __syncthreads();
        s[t] += tmp;
        __syncthreads();
    }
    if (t < NBUCK) { excl[t] = s[t] - v; cur[t] = s[t] - v; }
    if (t == 255) excl[NBUCK] = s[255];     // == n
    if (t < NBUCK) gb[t] = atomicAdd(&gtail[t], v);
    __syncthreads();

    // rank + reorder into bucket-sorted LDS buffer
#pragma unroll
    for (int i = 0; i < EPT; ++i) {
        if (bk[i] >= 0) {
            int r = atomicAdd(&cur[bk[i]], 1);
            reorder[r] = pk[i];
        }
    }
    __syncthreads();

    // copy out: consecutive i -> consecutive dst within each bucket run
    int total = excl[NBUCK];
    for (int i = t; i < total; i += 256) {
        int lo = 0, hi = NBUCK - 1;                  // largest b: excl[b] <= i
        while (lo < hi) {
            int mid = (lo + hi + 1) >> 1;
            if (excl[mid] <= i) lo = mid; else hi = mid - 1;
        }
        bin[gb[lo] + (i - excl[lo])] = reorder[i];
    }
}

// Phase B: one block per bucket. Counting-sort the bucket's entries into an
// LDS stage at exact csr ranks, then copy LDS -> csr fully coalesced.

__global__ __launch_bounds__(256) void k_csr(const unsigned int* __restrict__ bin,
                                             const int* __restrict__ offs,
                                             int* __restrict__ csr) {
    __shared__ unsigned int stage[CAP];
    __shared__ int sl[513];
    __shared__ int cnt[512];
    int b = blockIdx.x;
    int t = threadIdx.x;
    int nodeBase = b << BSH;
    int nNodes = N_NODES - nodeBase;
    if (nNodes > 512) nNodes = 512;
    int offBase = offs[nodeBase];
    for (int v = t; v <= nNodes; v += 256) sl[v] = offs[nodeBase + v] - offBase;
    for (int v = t; v < 512; v += 256) cnt[v] = 0;
    __syncthreads();
    int nE = sl[nNodes];
    for (int i = t; i < nE; i += 256) {
        unsigned int p = bin[offBase + i];
        int v   = (int)(p & 511u);
        int row = (int)(p >> BSH);
        int r = sl[v] + atomicAdd(&cnt[v], 1);
        if (r < CAP) stage[r] = (unsigned)row;
        else         csr[offBase + r] = row;         // overflow fallback (rare)
    }
    __syncthreads();
    int lim = nE < CAP ? nE : CAP;
    for (int i = t; i < lim; i += 256) csr[offBase + i] = (int)stage[i];
}

// ---------------- GEMM: h'[r] = dis[r] * (A[r] @ W) ----------------

__global__ __launch_bounds__(256) void k_gemm(const float* __restrict__ A,
                                              const float* __restrict__ W,
                                              const float* __restrict__ dis,
                                              float* __restrict__ out) {
    __shared__ float4 xs4[32 * 8];    // 32 rows x 32 k (as float4)
    __shared__ float4 ws4[32 * 32];   // 32 k x 128 cols (as float4)
    int t  = threadIdx.x;
    int tx = t & 31, ty = t >> 5;
    int rb = blockIdx.x * 32;
    const float4* A4 = (const float4*)A;
    const float4* W4 = (const float4*)W;
    float4 acc[4];
#pragma unroll
    for (int i = 0; i < 4; ++i) acc[i] = make_float4(0.f, 0.f, 0.f, 0.f);

    for (int kc = 0; kc < 4; ++kc) {
        {
            int r = t >> 3, c4 = t & 7;
            xs4[r * 8 + c4] = A4[(size_t)(rb + r) * 32 + kc * 8 + c4];
        }
#pragma unroll
        for (int i = 0; i < 4; ++i) {
            int idx = t + i * 256;
            int k = idx >> 5, c4 = idx & 31;
            ws4[k * 32 + c4] = W4[(size_t)(kc * 32 + k) * 32 + c4];
        }
        __syncthreads();
#pragma unroll
        for (int k0 = 0; k0 < 32; k0 += 4) {
            float4 b0 = ws4[(k0 + 0) * 32 + tx];
            float4 b1 = ws4[(k0 + 1) * 32 + tx];
            float4 b2 = ws4[(k0 + 2) * 32 + tx];
            float4 b3 = ws4[(k0 + 3) * 32 + tx];
#pragma unroll
            for (int i = 0; i < 4; ++i) {
                float4 a = xs4[(ty + 8 * i) * 8 + (k0 >> 2)];
                acc[i].x += a.x * b0.x; acc[i].y += a.x * b0.y;
                acc[i].z += a.x * b0.z; acc[i].w += a.x * b0.w;
                acc[i].x += a.y * b1.x; acc[i].y += a.y * b1.y;
                acc[i].z += a.y * b1.z; acc[i].w += a.y * b1.w;
                acc[i].x += a.z * b2.x; acc[i].y += a.z * b2.y;
                acc[i].z += a.z * b2.z; acc[i].w += a.z * b2.w;
                acc[i].x += a.w * b3.x; acc[i].y += a.w * b3.y;
                acc[i].z += a.w * b3.z; acc[i].w += a.w * b3.w;
            }
        }
        __syncthreads();
    }
    float4* O4 = (float4*)out;
#pragma unroll
    for (int i = 0; i < 4; ++i) {
        int r = rb + ty + 8 * i;
        float d = dis[r];
        float4 o = acc[i];
        o.x *= d; o.y *= d; o.z *= d; o.w *= d;
        O4[(size_t)r * 32 + tx] = o;
    }
}

// ---------------- aggregation ----------------
// one wave per node, lane owns features (2*lane, 2*lane+1); edge loop x8
// unrolled for 8 outstanding 512B row-gathers per wave.

template <bool RELU>
__global__ __launch_bounds__(256) void k_agg(const float* __restrict__ h,
                                             const int* __restrict__ csr,
                                             const int* __restrict__ offs,
                                             const float* __restrict__ dis,
                                             const float* __restrict__ bias,
                                             float* __restrict__ out) {
    int v    = blockIdx.x * 4 + (threadIdx.x >> 6);
    int lane = threadIdx.x & 63;
    const float2* h2 = (const float2*)h;
    float2 a0 = h2[(size_t)v * 64 + lane];       // self loop term (h'[v])
    float2 a1 = make_float2(0.f, 0.f);
    int s = offs[v], e = offs[v + 1];
    int i = s;
    for (; i + 8 <= e; i += 8) {
        int s0 = csr[i + 0], s1 = csr[i + 1], s2 = csr[i + 2], s3 = csr[i + 3];
        int s4 = csr[i + 4], s5 = csr[i + 5], s6 = csr[i + 6], s7 = csr[i + 7];
        float2 t0 = h2[(size_t)s0 * 64 + lane];
        float2 t1 = h2[(size_t)s1 * 64 + lane];
        float2 t2 = h2[(size_t)s2 * 64 + lane];
        float2 t3 = h2[(size_t)s3 * 64 + lane];
        float2 t4 = h2[(size_t)s4 * 64 + lane];
        float2 t5 = h2[(size_t)s5 * 64 + lane];
        float2 t6 = h2[(size_t)s6 * 64 + lane];
        float2 t7 = h2[(size_t)s7 * 64 + lane];
        a0.x += t0.x; a0.y += t0.y;  a1.x += t1.x; a1.y += t1.y;
        a0.x += t2.x; a0.y += t2.y;  a1.x += t3.x; a1.y += t3.y;
        a0.x += t4.x; a0.y += t4.y;  a1.x += t5.x; a1.y += t5.y;
        a0.x += t6.x; a0.y += t6.y;  a1.x += t7.x; a1.y += t7.y;
    }
    for (; i + 2 <= e; i += 2) {
        int s0 = csr[i], s1 = csr[i + 1];
        float2 t0 = h2[(size_t)s0 * 64 + lane];
        float2 t1 = h2[(size_t)s1 * 64 + lane];
        a0.x += t0.x; a0.y += t0.y;  a1.x += t1.x; a1.y += t1.y;
    }
    if (i < e) {
        int s0 = csr[i];
        float2 t0 = h2[(size_t)s0 * 64 + lane];
        a0.x += t0.x; a0.y += t0.y;
    }
    float dv = dis[v];
    float2 bb = ((const float2*)bias)[lane];
    float2 o;
    o.x = dv * (a0.x + a1.x) + bb.x;
    o.y = dv * (a0.y + a1.y) + bb.y;
    if (RELU) { o.x = fmaxf(o.x, 0.f); o.y = fmaxf(o.y, 0.f); }
    ((float2*)out)[(size_t)v * 64 + lane] = o;
}

// ---------------- launch ----------------

extern "C" void kernel_launch(void* const* d_in, const int* in_sizes, int n_in,
                              void* d_out, int out_size, void* d_ws, size_t ws_size,
                              hipStream_t stream) {
    const float* x     = (const float*)d_in[0];
    const int*   edges = (const int*)d_in[1];     // harness stages integers as int32
    const float* W1    = (const float*)d_in[2];
    const float* b1    = (const float*)d_in[3];
    const float* W2    = (const float*)d_in[4];
    const float* b2    = (const float*)d_in[5];
    float* out = (float*)d_out;
    const int E = in_sizes[1] / 2;

    // workspace carve (~58.5 MB)
    char* p = (char*)d_ws;
    auto alloc = [&](size_t bytes) -> char* {
        char* r = p;
        p += (bytes + 255) & ~(size_t)255;
        return r;
    };
    int*   counts = (int*)alloc((size_t)N_NODES * 4);
    int*   offs   = (int*)alloc((size_t)(N_NODES + 1) * 4);
    float* dis    = (float*)alloc((size_t)N_NODES * 4);
    int*   bsum   = (int*)alloc(256 * 4);
    int*   bbase  = (int*)alloc(256 * 4);
    int*   gtail  = (int*)alloc(256 * 4);
    int*   csr    = (int*)alloc((size_t)E * 4);
    float* hA     = (float*)alloc((size_t)N_NODES * 128 * 4);
    unsigned int* bin = (unsigned int*)hA;   // alias: bin dead before k_gemm writes hA

    const int NB = (N_NODES + 511) / 512;   // 196
    const int TILES = (E + TILE - 1) / TILE;

    k_zero<<<(N_NODES + 255) / 256, 256, 0, stream>>>(counts);
    k_hist<<<1024, 256, 0, stream>>>(edges, E, counts);
    k_scan1<<<NB, 512, 0, stream>>>(counts, offs, bsum);
    k_scan2<<<1, 256, 0, stream>>>(bsum, bbase, offs, NB);
    k_scan3<<<(N_NODES + 255) / 256, 256, 0, stream>>>(offs, bbase, counts, dis, gtail);
    k_binA<<<TILES, 256, 0, stream>>>(edges, E, gtail, bin);
    k_csr<<<NBUCK, 256, 0, stream>>>(bin, offs, csr);

    // layer 1: h' = dis * (x @ W1) -> hA ; aggregate(+b1, relu) -> out (temp)
    k_gemm<<<N_NODES / 32, 256, 0, stream>>>(x, W1, dis, hA);
    k_agg<true><<<N_NODES / 4, 256, 0, stream>>>(hA, csr, offs, dis, b1, out);

    // layer 2: h' = dis * (out @ W2) -> hA ; aggregate(+b2) -> out (final)
    k_gemm<<<N_NODES / 32, 256, 0, stream>>>(out, W2, dis, hA);
    k_agg<false><<<N_NODES / 4, 256, 0, stream>>>(hA, csr, offs, dis, b2, out);
}

// Round 10
// 536.185 us; speedup vs baseline: 1.3797x; 1.0132x over previous
//
#include <hip/hip_runtime.h>

#define N_NODES 100000
#define NBUCK 196        // ceil(100000 / 512) node buckets
#define BSH 9            // 512 nodes per bucket
#define TILE 4096        // edges per binning tile
#define EPT 16           // TILE / 256 threads
#define CAP 10240        // k_csr LDS stage capacity (mean 8192, sd ~90 -> 22 sigma)

// ---------------- preprocessing: degree / offsets ----------------

__global__ void k_zero(int* __restrict__ counts) {
    int i = blockIdx.x * 256 + threadIdx.x;
    if (i < N_NODES) counts[i] = 0;
}

__global__ void k_hist(const int* __restrict__ edges, int E,
                       int* __restrict__ counts) {
    int stride = gridDim.x * blockDim.x;
    for (int e = blockIdx.x * blockDim.x + threadIdx.x; e < E; e += stride) {
        int c = edges[E + e];               // col (target)
        atomicAdd(&counts[c], 1);
    }
}

// block-level exclusive scan (512 elems/block, Hillis-Steele)
__global__ void k_scan1(const int* __restrict__ counts, int* __restrict__ offs,
                        int* __restrict__ bsum) {
    __shared__ int s[512];
    int i = blockIdx.x * 512 + threadIdx.x;
    int v = (i < N_NODES) ? counts[i] : 0;
    s[threadIdx.x] = v;
    __syncthreads();
    for (int off = 1; off < 512; off <<= 1) {
        int t = (threadIdx.x >= off) ? s[threadIdx.x - off] : 0;
        __syncthreads();
        s[threadIdx.x] += t;
        __syncthreads();
    }
    if (i < N_NODES) offs[i] = s[threadIdx.x] - v;   // exclusive partial
    if (threadIdx.x == 511) bsum[blockIdx.x] = s[511];
}

// parallel scan of the 196 block sums (one block, LDS)
__global__ void k_scan2(const int* __restrict__ bsum, int* __restrict__ bbase,
                        int* __restrict__ offs, int nb) {
    __shared__ int s[256];
    int t = threadIdx.x;
    int v = (t < nb) ? bsum[t] : 0;
    s[t] = v;
    __syncthreads();
    for (int off = 1; off < 256; off <<= 1) {
        int tmp = (t >= off) ? s[t - off] : 0;
        __syncthreads();
        s[t] += tmp;
        __syncthreads();
    }
    if (t < nb) bbase[t] = s[t] - v;        // exclusive
    if (t == 255) offs[N_NODES] = s[255];   // = E
}

__global__ void k_scan3(int* __restrict__ offs, const int* __restrict__ bbase,
                        const int* __restrict__ counts, float* __restrict__ dis,
                        int* __restrict__ gtail) {
    int i = blockIdx.x * 256 + threadIdx.x;
    if (i < N_NODES) {
        int o = offs[i] + bbase[i >> 9];
        offs[i] = o;
        dis[i] = rsqrtf((float)(counts[i] + 1));   // +1: self loop
        if ((i & 511) == 0) gtail[i >> BSH] = o;   // bucket write cursor init
    }
}

// ---------------- CSR build, write-coalesced ----------------
// Phase A: tile-sort 4096 edges/block into 196 coarse buckets in LDS, then
// append bucket-runs (~84B contiguous) to global bin[] regions. Entry packed
// as (row<<9 | col&511), 4B.

__global__ __launch_bounds__(256) void k_binA(const int* __restrict__ edges, int E,
                                              int* __restrict__ gtail,
                                              unsigned int* __restrict__ bin) {
    __shared__ int cnt[NBUCK];
    __shared__ int excl[NBUCK + 1];
    __shared__ int cur[NBUCK];
    __shared__ int gb[NBUCK];
    __shared__ int s[256];
    __shared__ unsigned int reorder[TILE];

    int t = threadIdx.x;
    int base = blockIdx.x * TILE;
    for (int b = t; b < NBUCK; b += 256) cnt[b] = 0;
    __syncthreads();

    int n = E - base;
    if (n > TILE) n = TILE;

    unsigned int pk[EPT];
    int bk[EPT];
#pragma unroll
    for (int i = 0; i < EPT; ++i) {
        int idx = i * 256 + t;
        if (idx < n) {
            int e = base + idx;
            int r = edges[e];
            int c = edges[E + e];
            int b = c >> BSH;
            pk[i] = ((unsigned)r << BSH) | (unsigned)(c & 511);
            bk[i] = b;
            atomicAdd(&cnt[b], 1);
        } else {
            bk[i] = -1;
            pk[i] = 0;
        }
    }
    __syncthreads();

    // exclusive scan of cnt[0..195] (Hillis-Steele over 256)
    int v = (t < NBUCK) ? cnt[t] : 0;
    s[t] = v;
    __syncthreads();
    for (int off = 1; off < 256; off <<= 1) {
        int tmp = (t >= off) ? s[t - off] : 0;
        __syncthreads();
        s[t] += tmp;
        __syncthreads();
    }
    if (t < NBUCK) { excl[t] = s[t] - v; cur[t] = s[t] - v; }
    if (t == 255) excl[NBUCK] = s[255];     // == n
    if (t < NBUCK) gb[t] = atomicAdd(&gtail[t], v);
    __syncthreads();

    // rank + reorder into bucket-sorted LDS buffer
#pragma unroll
    for (int i = 0; i < EPT; ++i) {
        if (bk[i] >= 0) {
            int r = atomicAdd(&cur[bk[i]], 1);
            reorder[r] = pk[i];
        }
    }
    __syncthreads();

    // copy out: consecutive i -> consecutive dst within each bucket run
    int total = excl[NBUCK];
    for (int i = t; i < total; i += 256) {
        int lo = 0, hi = NBUCK - 1;                  // largest b: excl[b] <= i
        while (lo < hi) {
            int mid = (lo + hi + 1) >> 1;
            if (excl[mid] <= i) lo = mid; else hi = mid - 1;
        }
        bin[gb[lo] + (i - excl[lo])] = reorder[i];
    }
}

// Phase B: one block per bucket. Counting-sort the bucket's entries into an
// LDS stage at exact csr ranks, then copy LDS -> csr fully coalesced.

__global__ __launch_bounds__(256) void k_csr(const unsigned int* __restrict__ bin,
                                             const int* __restrict__ offs,
                                             int* __restrict__ csr) {
    __shared__ unsigned int stage[CAP];
    __shared__ int sl[513];
    __shared__ int cnt[512];
    int b = blockIdx.x;
    int t = threadIdx.x;
    int nodeBase = b << BSH;
    int nNodes = N_NODES - nodeBase;
    if (nNodes > 512) nNodes = 512;
    int offBase = offs[nodeBase];
    for (int v = t; v <= nNodes; v += 256) sl[v] = offs[nodeBase + v] - offBase;
    for (int v = t; v < 512; v += 256) cnt[v] = 0;
    __syncthreads();
    int nE = sl[nNodes];
    for (int i = t; i < nE; i += 256) {
        unsigned int p = bin[offBase + i];
        int v   = (int)(p & 511u);
        int row = (int)(p >> BSH);
        int r = sl[v] + atomicAdd(&cnt[v], 1);
        if (r < CAP) stage[r] = (unsigned)row;
        else         csr[offBase + r] = row;         // overflow fallback (rare)
    }
    __syncthreads();
    int lim = nE < CAP ? nE : CAP;
    for (int i = t; i < lim; i += 256) csr[offBase + i] = (int)stage[i];
}

// ---------------- GEMM: h'[r] = dis[r] * (A[r] @ W) ----------------

__global__ __launch_bounds__(256) void k_gemm(const float* __restrict__ A,
                                              const float* __restrict__ W,
                                              const float* __restrict__ dis,
                                              float* __restrict__ out) {
    __shared__ float4 xs4[32 * 8];    // 32 rows x 32 k (as float4)
    __shared__ float4 ws4[32 * 32];   // 32 k x 128 cols (as float4)
    int t  = threadIdx.x;
    int tx = t & 31, ty = t >> 5;
    int rb = blockIdx.x * 32;
    const float4* A4 = (const float4*)A;
    const float4* W4 = (const float4*)W;
    float4 acc[4];
#pragma unroll
    for (int i = 0; i < 4; ++i) acc[i] = make_float4(0.f, 0.f, 0.f, 0.f);

    for (int kc = 0; kc < 4; ++kc) {
        {
            int r = t >> 3, c4 = t & 7;
            xs4[r * 8 + c4] = A4[(size_t)(rb + r) * 32 + kc * 8 + c4];
        }
#pragma unroll
        for (int i = 0; i < 4; ++i) {
            int idx = t + i * 256;
            int k = idx >> 5, c4 = idx & 31;
            ws4[k * 32 + c4] = W4[(size_t)(kc * 32 + k) * 32 + c4];
        }
        __syncthreads();
#pragma unroll
        for (int k0 = 0; k0 < 32; k0 += 4) {
            float4 b0 = ws4[(k0 + 0) * 32 + tx];
            float4 b1 = ws4[(k0 + 1) * 32 + tx];
            float4 b2 = ws4[(k0 + 2) * 32 + tx];
            float4 b3 = ws4[(k0 + 3) * 32 + tx];
#pragma unroll
            for (int i = 0; i < 4; ++i) {
                float4 a = xs4[(ty + 8 * i) * 8 + (k0 >> 2)];
                acc[i].x += a.x * b0.x; acc[i].y += a.x * b0.y;
                acc[i].z += a.x * b0.z; acc[i].w += a.x * b0.w;
                acc[i].x += a.y * b1.x; acc[i].y += a.y * b1.y;
                acc[i].z += a.y * b1.z; acc[i].w += a.y * b1.w;
                acc[i].x += a.z * b2.x; acc[i].y += a.z * b2.y;
                acc[i].z += a.z * b2.z; acc[i].w += a.z * b2.w;
                acc[i].x += a.w * b3.x; acc[i].y += a.w * b3.y;
                acc[i].z += a.w * b3.z; acc[i].w += a.w * b3.w;
            }
        }
        __syncthreads();
    }
    float4* O4 = (float4*)out;
#pragma unroll
    for (int i = 0; i < 4; ++i) {
        int r = rb + ty + 8 * i;
        float d = dis[r];
        float4 o = acc[i];
        o.x *= d; o.y *= d; o.z *= d; o.w *= d;
        O4[(size_t)r * 32 + tx] = o;
    }
}

// ---------------- aggregation ----------------
// one wave per node; float4 gathers: 32 lanes cover one 512B row, so each
// load instruction fetches TWO neighbor rows (lane half = lane>>5 picks
// even/odd). Unroll 8 pairs -> 16 rows in flight per wave (was 8 float2).
// Cross-half __shfl_xor(32) reduce at the end; lanes<32 store the row.

template <bool RELU>
__global__ __launch_bounds__(256) void k_agg(const float* __restrict__ h,
                                             const int* __restrict__ csr,
                                             const int* __restrict__ offs,
                                             const float* __restrict__ dis,
                                             const float* __restrict__ bias,
                                             float* __restrict__ out) {
    int v    = blockIdx.x * 4 + (threadIdx.x >> 6);
    int lane = threadIdx.x & 63;
    int half = lane >> 5;
    int c4   = lane & 31;
    const float4* h4 = (const float4*)h;
    float4 acc = make_float4(0.f, 0.f, 0.f, 0.f);
    if (half == 0) acc = h4[(size_t)v * 32 + c4];   // self loop term, once
    int s = offs[v], e = offs[v + 1];
    int i = s;
    for (; i + 16 <= e; i += 16) {
        int s0 = csr[i +  0 + half], s1 = csr[i +  2 + half];
        int s2 = csr[i +  4 + half], s3 = csr[i +  6 + half];
        int s4 = csr[i +  8 + half], s5 = csr[i + 10 + half];
        int s6 = csr[i + 12 + half], s7 = csr[i + 14 + half];
        float4 t0 = h4[(size_t)s0 * 32 + c4];
        float4 t1 = h4[(size_t)s1 * 32 + c4];
        float4 t2 = h4[(size_t)s2 * 32 + c4];
        float4 t3 = h4[(size_t)s3 * 32 + c4];
        float4 t4 = h4[(size_t)s4 * 32 + c4];
        float4 t5 = h4[(size_t)s5 * 32 + c4];
        float4 t6 = h4[(size_t)s6 * 32 + c4];
        float4 t7 = h4[(size_t)s7 * 32 + c4];
        acc.x += t0.x; acc.y += t0.y; acc.z += t0.z; acc.w += t0.w;
        acc.x += t1.x; acc.y += t1.y; acc.z += t1.z; acc.w += t1.w;
        acc.x += t2.x; acc.y += t2.y; acc.z += t2.z; acc.w += t2.w;
        acc.x += t3.x; acc.y += t3.y; acc.z += t3.z; acc.w += t3.w;
        acc.x += t4.x; acc.y += t4.y; acc.z += t4.z; acc.w += t4.w;
        acc.x += t5.x; acc.y += t5.y; acc.z += t5.z; acc.w += t5.w;
        acc.x += t6.x; acc.y += t6.y; acc.z += t6.z; acc.w += t6.w;
        acc.x += t7.x; acc.y += t7.y; acc.z += t7.z; acc.w += t7.w;
    }
    for (; i + 2 <= e; i += 2) {
        int s0 = csr[i + half];
        float4 t0 = h4[(size_t)s0 * 32 + c4];
        acc.x += t0.x; acc.y += t0.y; acc.z += t0.z; acc.w += t0.w;
    }
    if (i < e && half == 0) {                        // odd leftover row
        int s0 = csr[i];
        float4 t0 = h4[(size_t)s0 * 32 + c4];
        acc.x += t0.x; acc.y += t0.y; acc.z += t0.z; acc.w += t0.w;
    }
    // reduce the two halves (lane L <-> L+32 hold same features)
    acc.x += __shfl_xor(acc.x, 32, 64);
    acc.y += __shfl_xor(acc.y, 32, 64);
    acc.z += __shfl_xor(acc.z, 32, 64);
    acc.w += __shfl_xor(acc.w, 32, 64);
    if (half == 0) {
        float dv = dis[v];
        float4 bb = ((const float4*)bias)[c4];
        float4 o;
        o.x = dv * acc.x + bb.x;
        o.y = dv * acc.y + bb.y;
        o.z = dv * acc.z + bb.z;
        o.w = dv * acc.w + bb.w;
        if (RELU) {
            o.x = fmaxf(o.x, 0.f); o.y = fmaxf(o.y, 0.f);
            o.z = fmaxf(o.z, 0.f); o.w = fmaxf(o.w, 0.f);
        }
        ((float4*)out)[(size_t)v * 32 + c4] = o;
    }
}

// ---------------- launch ----------------

extern "C" void kernel_launch(void* const* d_in, const int* in_sizes, int n_in,
                              void* d_out, int out_size, void* d_ws, size_t ws_size,
                              hipStream_t stream) {
    const float* x     = (const float*)d_in[0];
    const int*   edges = (const int*)d_in[1];     // harness stages integers as int32
    const float* W1    = (const float*)d_in[2];
    const float* b1    = (const float*)d_in[3];
    const float* W2    = (const float*)d_in[4];
    const float* b2    = (const float*)d_in[5];
    float* out = (float*)d_out;
    const int E = in_sizes[1] / 2;

    // workspace carve (~58.5 MB)
    char* p = (char*)d_ws;
    auto alloc = [&](size_t bytes) -> char* {
        char* r = p;
        p += (bytes + 255) & ~(size_t)255;
        return r;
    };
    int*   counts = (int*)alloc((size_t)N_NODES * 4);
    int*   offs   = (int*)alloc((size_t)(N_NODES + 1) * 4);
    float* dis    = (float*)alloc((size_t)N_NODES * 4);
    int*   bsum   = (int*)alloc(256 * 4);
    int*   bbase  = (int*)alloc(256 * 4);
    int*   gtail  = (int*)alloc(256 * 4);
    int*   csr    = (int*)alloc((size_t)E * 4);
    float* hA     = (float*)alloc((size_t)N_NODES * 128 * 4);
    unsigned int* bin = (unsigned int*)hA;   // alias: bin dead before k_gemm writes hA

    const int NB = (N_NODES + 511) / 512;   // 196
    const int TILES = (E + TILE - 1) / TILE;

    k_zero<<<(N_NODES + 255) / 256, 256, 0, stream>>>(counts);
    k_hist<<<1024, 256, 0, stream>>>(edges, E, counts);
    k_scan1<<<NB, 512, 0, stream>>>(counts, offs, bsum);
    k_scan2<<<1, 256, 0, stream>>>(bsum, bbase, offs, NB);
    k_scan3<<<(N_NODES + 255) / 256, 256, 0, stream>>>(offs, bbase, counts, dis, gtail);
    k_binA<<<TILES, 256, 0, stream>>>(edges, E, gtail, bin);
    k_csr<<<NBUCK, 256, 0, stream>>>(bin, offs, csr);

    // layer 1: h' = dis * (x @ W1) -> hA ; aggregate(+b1, relu) -> out (temp)
    k_gemm<<<N_NODES / 32, 256, 0, stream>>>(x, W1, dis, hA);
    k_agg<true><<<N_NODES / 4, 256, 0, stream>>>(hA, csr, offs, dis, b1, out);

    // layer 2: h' = dis * (out @ W2) -> hA ; aggregate(+b2) -> out (final)
    k_gemm<<<N_NODES / 32, 256, 0, stream>>>(out, W2, dis, hA);
    k_agg<false><<<N_NODES / 4, 256, 0, stream>>>(hA, csr, offs, dis, b2, out);
}

// Round 12
// 463.229 us; speedup vs baseline: 1.5970x; 1.1575x over previous
//
#include <hip/hip_runtime.h>
#include <hip/hip_fp16.h>

#define N_NODES 100000
#define NBUCK 196        // ceil(100000 / 512) node buckets
#define BSH 9            // 512 nodes per bucket
#define TILE 4096        // edges per binning tile
#define EPT 16           // TILE / 256 threads
#define CAP 10240        // k_csr LDS stage capacity (mean 8192, sd ~90 -> 22 sigma)

// ---------------- preprocessing: degree / offsets ----------------

__global__ void k_zero(int* __restrict__ counts) {
    int i = blockIdx.x * 256 + threadIdx.x;
    if (i < N_NODES) counts[i] = 0;
}

__global__ void k_hist(const int* __restrict__ edges, int E,
                       int* __restrict__ counts) {
    int stride = gridDim.x * blockDim.x;
    for (int e = blockIdx.x * blockDim.x + threadIdx.x; e < E; e += stride) {
        int c = edges[E + e];               // col (target)
        atomicAdd(&counts[c], 1);
    }
}

// block-level exclusive scan (512 elems/block, Hillis-Steele)
__global__ void k_scan1(const int* __restrict__ counts, int* __restrict__ offs,
                        int* __restrict__ bsum) {
    __shared__ int s[512];
    int i = blockIdx.x * 512 + threadIdx.x;
    int v = (i < N_NODES) ? counts[i] : 0;
    s[threadIdx.x] = v;
    __syncthreads();
    for (int off = 1; off < 512; off <<= 1) {
        int t = (threadIdx.x >= off) ? s[threadIdx.x - off] : 0;
        __syncthreads();
        s[threadIdx.x] += t;
        __syncthreads();
    }
    if (i < N_NODES) offs[i] = s[threadIdx.x] - v;   // exclusive partial
    if (threadIdx.x == 511) bsum[blockIdx.x] = s[511];
}

// parallel scan of the 196 block sums (one block, LDS)
__global__ void k_scan2(const int* __restrict__ bsum, int* __restrict__ bbase,
                        int* __restrict__ offs, int nb) {
    __shared__ int s[256];
    int t = threadIdx.x;
    int v = (t < nb) ? bsum[t] : 0;
    s[t] = v;
    __syncthreads();
    for (int off = 1; off < 256; off <<= 1) {
        int tmp = (t >= off) ? s[t - off] : 0;
        __syncthreads();
        s[t] += tmp;
        __syncthreads();
    }
    if (t < nb) bbase[t] = s[t] - v;        // exclusive
    if (t == 255) offs[N_NODES] = s[255];   // = E
}

__global__ void k_scan3(int* __restrict__ offs, const int* __restrict__ bbase,
                        const int* __restrict__ counts, float* __restrict__ dis,
                        int* __restrict__ gtail) {
    int i = blockIdx.x * 256 + threadIdx.x;
    if (i < N_NODES) {
        int o = offs[i] + bbase[i >> 9];
        offs[i] = o;
        dis[i] = rsqrtf((float)(counts[i] + 1));   // +1: self loop
        if ((i & 511) == 0) gtail[i >> BSH] = o;   // bucket write cursor init
    }
}

// ---------------- CSR build, write-coalesced ----------------

__global__ __launch_bounds__(256) void k_binA(const int* __restrict__ edges, int E,
                                              int* __restrict__ gtail,
                                              unsigned int* __restrict__ bin) {
    __shared__ int cnt[NBUCK];
    __shared__ int excl[NBUCK + 1];
    __shared__ int cur[NBUCK];
    __shared__ int gb[NBUCK];
    __shared__ int s[256];
    __shared__ unsigned int reorder[TILE];

    int t = threadIdx.x;
    int base = blockIdx.x * TILE;
    for (int b = t; b < NBUCK; b += 256) cnt[b] = 0;
    __syncthreads();

    int n = E - base;
    if (n > TILE) n = TILE;

    unsigned int pk[EPT];
    int bk[EPT];
#pragma unroll
    for (int i = 0; i < EPT; ++i) {
        int idx = i * 256 + t;
        if (idx < n) {
            int e = base + idx;
            int r = edges[e];
            int c = edges[E + e];
            int b = c >> BSH;
            pk[i] = ((unsigned)r << BSH) | (unsigned)(c & 511);
            bk[i] = b;
            atomicAdd(&cnt[b], 1);
        } else {
            bk[i] = -1;
            pk[i] = 0;
        }
    }
    __syncthreads();

    // exclusive scan of cnt[0..195] (Hillis-Steele over 256)
    int v = (t < NBUCK) ? cnt[t] : 0;
    s[t] = v;
    __syncthreads();
    for (int off = 1; off < 256; off <<= 1) {
        int tmp = (t >= off) ? s[t - off] : 0;
        __syncthreads();
        s[t] += tmp;
        __syncthreads();
    }
    if (t < NBUCK) { excl[t] = s[t] - v; cur[t] = s[t] - v; }
    if (t == 255) excl[NBUCK] = s[255];     // == n
    if (t < NBUCK) gb[t] = atomicAdd(&gtail[t], v);
    __syncthreads();

    // rank + reorder into bucket-sorted LDS buffer
#pragma unroll
    for (int i = 0; i < EPT; ++i) {
        if (bk[i] >= 0) {
            int r = atomicAdd(&cur[bk[i]], 1);
            reorder[r] = pk[i];
        }
    }
    __syncthreads();

    // copy out: consecutive i -> consecutive dst within each bucket run
    int total = excl[NBUCK];
    for (int i = t; i < total; i += 256) {
        int lo = 0, hi = NBUCK - 1;                  // largest b: excl[b] <= i
        while (lo < hi) {
            int mid = (lo + hi + 1) >> 1;
            if (excl[mid] <= i) lo = mid; else hi = mid - 1;
        }
        bin[gb[lo] + (i - excl[lo])] = reorder[i];
    }
}

// Phase B: one block per bucket; counting-sort into LDS, coalesced copy out.

__global__ __launch_bounds__(256) void k_csr(const unsigned int* __restrict__ bin,
                                             const int* __restrict__ offs,
                                             int* __restrict__ csr) {
    __shared__ unsigned int stage[CAP];
    __shared__ int sl[513];
    __shared__ int cnt[512];
    int b = blockIdx.x;
    int t = threadIdx.x;
    int nodeBase = b << BSH;
    int nNodes = N_NODES - nodeBase;
    if (nNodes > 512) nNodes = 512;
    int offBase = offs[nodeBase];
    for (int v = t; v <= nNodes; v += 256) sl[v] = offs[nodeBase + v] - offBase;
    for (int v = t; v < 512; v += 256) cnt[v] = 0;
    __syncthreads();
    int nE = sl[nNodes];
    for (int i = t; i < nE; i += 256) {
        unsigned int p = bin[offBase + i];
        int v   = (int)(p & 511u);
        int row = (int)(p >> BSH);
        int r = sl[v] + atomicAdd(&cnt[v], 1);
        if (r < CAP) stage[r] = (unsigned)row;
        else         csr[offBase + r] = row;         // overflow fallback (rare)
    }
    __syncthreads();
    int lim = nE < CAP ? nE : CAP;
    for (int i = t; i < lim; i += 256) csr[offBase + i] = (int)stage[i];
}

// ---------------- GEMM: h16[r] = fp16( dis[r] * (A[r] @ W) ) ----------------
// fp32 accumulate, fp16 packed output (gathered matrix rows are now 256B:
// halves the L2-fill traffic that bounds k_agg at 3.9 TB/s).

__global__ __launch_bounds__(256) void k_gemm(const float* __restrict__ A,
                                              const float* __restrict__ W,
                                              const float* __restrict__ dis,
                                              uint2* __restrict__ out16) {
    __shared__ float4 xs4[32 * 8];    // 32 rows x 32 k (as float4)
    __shared__ float4 ws4[32 * 32];   // 32 k x 128 cols (as float4)
    int t  = threadIdx.x;
    int tx = t & 31, ty = t >> 5;
    int rb = blockIdx.x * 32;
    const float4* A4 = (const float4*)A;
    const float4* W4 = (const float4*)W;
    float4 acc[4];
#pragma unroll
    for (int i = 0; i < 4; ++i) acc[i] = make_float4(0.f, 0.f, 0.f, 0.f);

    for (int kc = 0; kc < 4; ++kc) {
        {
            int r = t >> 3, c4 = t & 7;
            xs4[r * 8 + c4] = A4[(size_t)(rb + r) * 32 + kc * 8 + c4];
        }
#pragma unroll
        for (int i = 0; i < 4; ++i) {
            int idx = t + i * 256;
            int k = idx >> 5, c4 = idx & 31;
            ws4[k * 32 + c4] = W4[(size_t)(kc * 32 + k) * 32 + c4];
        }
        __syncthreads();
#pragma unroll
        for (int k0 = 0; k0 < 32; k0 += 4) {
            float4 b0 = ws4[(k0 + 0) * 32 + tx];
            float4 b1 = ws4[(k0 + 1) * 32 + tx];
            float4 b2 = ws4[(k0 + 2) * 32 + tx];
            float4 b3 = ws4[(k0 + 3) * 32 + tx];
#pragma unroll
            for (int i = 0; i < 4; ++i) {
                float4 a = xs4[(ty + 8 * i) * 8 + (k0 >> 2)];
                acc[i].x += a.x * b0.x; acc[i].y += a.x * b0.y;
                acc[i].z += a.x * b0.z; acc[i].w += a.x * b0.w;
                acc[i].x += a.y * b1.x; acc[i].y += a.y * b1.y;
                acc[i].z += a.y * b1.z; acc[i].w += a.y * b1.w;
                acc[i].x += a.z * b2.x; acc[i].y += a.z * b2.y;
                acc[i].z += a.z * b2.z; acc[i].w += a.z * b2.w;
                acc[i].x += a.w * b3.x; acc[i].y += a.w * b3.y;
                acc[i].z += a.w * b3.z; acc[i].w += a.w * b3.w;
            }
        }
        __syncthreads();
    }
#pragma unroll
    for (int i = 0; i < 4; ++i) {
        int r = rb + ty + 8 * i;
        float d = dis[r];
        float4 o = acc[i];
        union { __half2 h2[2]; uint2 u; } cvt;
        cvt.h2[0] = __floats2half2_rn(d * o.x, d * o.y);
        cvt.h2[1] = __floats2half2_rn(d * o.z, d * o.w);
        out16[(size_t)r * 32 + tx] = cvt.u;          // 8B/lane, coalesced 256B row
    }
}

// ---------------- aggregation ----------------
// one wave per node; fp16 rows (256B): 32 lanes x uint2(4 halves) cover one
// row, each load instruction fetches TWO neighbor rows (lane half = lane>>5).
// Unroll 8 pairs -> 16 rows in flight. fp32 accumulate; cross-half shfl_xor.

__device__ __forceinline__ float4 h2f4(uint2 p) {
    __half2 a = *reinterpret_cast<__half2*>(&p.x);
    __half2 b = *reinterpret_cast<__half2*>(&p.y);
    float2 fa = __half22float2(a);
    float2 fb = __half22float2(b);
    return make_float4(fa.x, fa.y, fb.x, fb.y);
}

template <bool RELU>
__global__ __launch_bounds__(256) void k_agg(const uint2* __restrict__ h16,
                                             const int* __restrict__ csr,
                                             const int* __restrict__ offs,
                                             const float* __restrict__ dis,
                                             const float* __restrict__ bias,
                                             float* __restrict__ out) {
    int v    = blockIdx.x * 4 + (threadIdx.x >> 6);
    int lane = threadIdx.x & 63;
    int half = lane >> 5;
    int c4   = lane & 31;
    float4 acc = make_float4(0.f, 0.f, 0.f, 0.f);
    if (half == 0) {                                 // self loop term, once
        float4 sv = h2f4(h16[(size_t)v * 32 + c4]);
        acc = sv;
    }
    int s = offs[v], e = offs[v + 1];
    int i = s;
    for (; i + 16 <= e; i += 16) {
        int s0 = csr[i +  0 + half], s1 = csr[i +  2 + half];
        int s2 = csr[i +  4 + half], s3 = csr[i +  6 + half];
        int s4 = csr[i +  8 + half], s5 = csr[i + 10 + half];
        int s6 = csr[i + 12 + half], s7 = csr[i + 14 + half];
        uint2 p0 = h16[(size_t)s0 * 32 + c4];
        uint2 p1 = h16[(size_t)s1 * 32 + c4];
        uint2 p2 = h16[(size_t)s2 * 32 + c4];
        uint2 p3 = h16[(size_t)s3 * 32 + c4];
        uint2 p4 = h16[(size_t)s4 * 32 + c4];
        uint2 p5 = h16[(size_t)s5 * 32 + c4];
        uint2 p6 = h16[(size_t)s6 * 32 + c4];
        uint2 p7 = h16[(size_t)s7 * 32 + c4];
        float4 t0 = h2f4(p0), t1 = h2f4(p1), t2 = h2f4(p2), t3 = h2f4(p3);
        float4 t4 = h2f4(p4), t5 = h2f4(p5), t6 = h2f4(p6), t7 = h2f4(p7);
        acc.x += t0.x; acc.y += t0.y; acc.z += t0.z; acc.w += t0.w;
        acc.x += t1.x; acc.y += t1.y; acc.z += t1.z; acc.w += t1.w;
        acc.x += t2.x; acc.y += t2.y; acc.z += t2.z; acc.w += t2.w;
        acc.x += t3.x; acc.y += t3.y; acc.z += t3.z; acc.w += t3.w;
        acc.x += t4.x; acc.y += t4.y; acc.z += t4.z; acc.w += t4.w;
        acc.x += t5.x; acc.y += t5.y; acc.z += t5.z; acc.w += t5.w;
        acc.x += t6.x; acc.y += t6.y; acc.z += t6.z; acc.w += t6.w;
        acc.x += t7.x; acc.y += t7.y; acc.z += t7.z; acc.w += t7.w;
    }
    for (; i + 2 <= e; i += 2) {
        int s0 = csr[i + half];
        float4 t0 = h2f4(h16[(size_t)s0 * 32 + c4]);
        acc.x += t0.x; acc.y += t0.y; acc.z += t0.z; acc.w += t0.w;
    }
    if (i < e && half == 0) {                        // odd leftover row
        int s0 = csr[i];
        float4 t0 = h2f4(h16[(size_t)s0 * 32 + c4]);
        acc.x += t0.x; acc.y += t0.y; acc.z += t0.z; acc.w += t0.w;
    }
    // reduce the two halves (lane L <-> L+32 hold same features)
    acc.x += __shfl_xor(acc.x, 32, 64);
    acc.y += __shfl_xor(acc.y, 32, 64);
    acc.z += __shfl_xor(acc.z, 32, 64);
    acc.w += __shfl_xor(acc.w, 32, 64);
    if (half == 0) {
        float dv = dis[v];
        float4 bb = ((const float4*)bias)[c4];
        float4 o;
        o.x = dv * acc.x + bb.x;
        o.y = dv * acc.y + bb.y;
        o.z = dv * acc.z + bb.z;
        o.w = dv * acc.w + bb.w;
        if (RELU) {
            o.x = fmaxf(o.x, 0.f); o.y = fmaxf(o.y, 0.f);
            o.z = fmaxf(o.z, 0.f); o.w = fmaxf(o.w, 0.f);
        }
        ((float4*)out)[(size_t)v * 32 + c4] = o;
    }
}

// ---------------- launch ----------------

extern "C" void kernel_launch(void* const* d_in, const int* in_sizes, int n_in,
                              void* d_out, int out_size, void* d_ws, size_t ws_size,
                              hipStream_t stream) {
    const float* x     = (const float*)d_in[0];
    const int*   edges = (const int*)d_in[1];     // harness stages integers as int32
    const float* W1    = (const float*)d_in[2];
    const float* b1    = (const float*)d_in[3];
    const float* W2    = (const float*)d_in[4];
    const float* b2    = (const float*)d_in[5];
    float* out = (float*)d_out;
    const int E = in_sizes[1] / 2;

    // workspace carve (~33 MB)
    char* p = (char*)d_ws;
    auto alloc = [&](size_t bytes) -> char* {
        char* r = p;
        p += (bytes + 255) & ~(size_t)255;
        return r;
    };
    int*   counts = (int*)alloc((size_t)N_NODES * 4);
    int*   offs   = (int*)alloc((size_t)(N_NODES + 1) * 4);
    float* dis    = (float*)alloc((size_t)N_NODES * 4);
    int*   bsum   = (int*)alloc(256 * 4);
    int*   bbase  = (int*)alloc(256 * 4);
    int*   gtail  = (int*)alloc(256 * 4);
    int*   csr    = (int*)alloc((size_t)E * 4);
    uint2* h16    = (uint2*)alloc((size_t)N_NODES * 128 * 2);   // fp16 h'
    unsigned int* bin = (unsigned int*)h16;  // alias: bin dead before k_gemm writes h16

    const int NB = (N_NODES + 511) / 512;   // 196
    const int TILES = (E + TILE - 1) / TILE;

    k_zero<<<(N_NODES + 255) / 256, 256, 0, stream>>>(counts);
    k_hist<<<1024, 256, 0, stream>>>(edges, E, counts);
    k_scan1<<<NB, 512, 0, stream>>>(counts, offs, bsum);
    k_scan2<<<1, 256, 0, stream>>>(bsum, bbase, offs, NB);
    k_scan3<<<(N_NODES + 255) / 256, 256, 0, stream>>>(offs, bbase, counts, dis, gtail);
    k_binA<<<TILES, 256, 0, stream>>>(edges, E, gtail, bin);
    k_csr<<<NBUCK, 256, 0, stream>>>(bin, offs, csr);

    // layer 1: h16 = fp16(dis * (x @ W1)) ; aggregate(+b1, relu) -> out (temp)
    k_gemm<<<N_NODES / 32, 256, 0, stream>>>(x, W1, dis, h16);
    k_agg<true><<<N_NODES / 4, 256, 0, stream>>>(h16, csr, offs, dis, b1, out);

    // layer 2: h16 = fp16(dis * (out @ W2)) ; aggregate(+b2) -> out (final)
    k_gemm<<<N_NODES / 32, 256, 0, stream>>>(out, W2, dis, h16);
    k_agg<false><<<N_NODES / 4, 256, 0, stream>>>(h16, csr, offs, dis, b2, out);
}

// Round 13
// 398.616 us; speedup vs baseline: 1.8558x; 1.1621x over previous
//
#include <hip/hip_runtime.h>
#include <hip/hip_fp16.h>

#define N_NODES 100000
#define NBUCK 196        // ceil(100000 / 512) node buckets
#define BSH 9            // 512 nodes per bucket
#define TILE 4096        // edges per binning tile
#define EPT 16           // TILE / 256 threads
#define CAP 10240        // k_csr2 LDS stage capacity (bucket mean 8192, sd ~90)
#define CAPB 16384       // padded per-bucket bin region (2x mean -> ~90 sigma)

// ---------------- CSR build, write-coalesced, no node-level pre-scan ----------------
// k_init: zero the 196 bucket tails.
// k_binP: tile-sort 4096 edges/block into 196 buckets in LDS, append runs to
//         padded global regions binP[b*CAPB ...] (per-bucket tail atomics only).
// k_scanB: 196-element scan -> bucketBase (absolute csr offsets).
// k_csr2: per bucket: count nodes, pair-scan 512 -> node offsets; write offs,
//         dis, and counting-sorted csr (LDS stage, coalesced out).

__global__ void k_init(int* __restrict__ tails) {
    if (threadIdx.x < NBUCK) tails[threadIdx.x] = 0;
}

__global__ __launch_bounds__(256) void k_binP(const int* __restrict__ edges, int E,
                                              int* __restrict__ tails,
                                              unsigned int* __restrict__ binP) {
    __shared__ int cnt[NBUCK];
    __shared__ int excl[NBUCK + 1];
    __shared__ int cur[NBUCK];
    __shared__ int gb[NBUCK];
    __shared__ int s[256];
    __shared__ unsigned int reorder[TILE];

    int t = threadIdx.x;
    int base = blockIdx.x * TILE;
    for (int b = t; b < NBUCK; b += 256) cnt[b] = 0;
    __syncthreads();

    int n = E - base;
    if (n > TILE) n = TILE;

    unsigned int pk[EPT];
    int bk[EPT];
#pragma unroll
    for (int i = 0; i < EPT; ++i) {
        int idx = i * 256 + t;
        if (idx < n) {
            int e = base + idx;
            int r = edges[e];
            int c = edges[E + e];
            int b = c >> BSH;
            pk[i] = ((unsigned)r << BSH) | (unsigned)(c & 511);
            bk[i] = b;
            atomicAdd(&cnt[b], 1);
        } else {
            bk[i] = -1;
            pk[i] = 0;
        }
    }
    __syncthreads();

    // exclusive scan of cnt[0..195] (Hillis-Steele over 256)
    int v = (t < NBUCK) ? cnt[t] : 0;
    s[t] = v;
    __syncthreads();
    for (int off = 1; off < 256; off <<= 1) {
        int tmp = (t >= off) ? s[t - off] : 0;
        __syncthreads();
        s[t] += tmp;
        __syncthreads();
    }
    if (t < NBUCK) { excl[t] = s[t] - v; cur[t] = s[t] - v; }
    if (t == 255) excl[NBUCK] = s[255];     // == n
    if (t < NBUCK) gb[t] = atomicAdd(&tails[t], v);
    __syncthreads();

    // rank + reorder into bucket-sorted LDS buffer
#pragma unroll
    for (int i = 0; i < EPT; ++i) {
        if (bk[i] >= 0) {
            int r = atomicAdd(&cur[bk[i]], 1);
            reorder[r] = pk[i];
        }
    }
    __syncthreads();

    // copy out: consecutive i -> consecutive dst within each bucket run
    int total = excl[NBUCK];
    for (int i = t; i < total; i += 256) {
        int lo = 0, hi = NBUCK - 1;                  // largest b: excl[b] <= i
        while (lo < hi) {
            int mid = (lo + hi + 1) >> 1;
            if (excl[mid] <= i) lo = mid; else hi = mid - 1;
        }
        int dst = gb[lo] + (i - excl[lo]);
        if (dst < CAPB)                              // ~90-sigma guard
            binP[(size_t)lo * CAPB + dst] = reorder[i];
    }
}

__global__ void k_scanB(const int* __restrict__ tails,
                        int* __restrict__ bucketBase) {
    __shared__ int s[256];
    int t = threadIdx.x;
    int v = (t < NBUCK) ? tails[t] : 0;
    s[t] = v;
    __syncthreads();
    for (int off = 1; off < 256; off <<= 1) {
        int tmp = (t >= off) ? s[t - off] : 0;
        __syncthreads();
        s[t] += tmp;
        __syncthreads();
    }
    if (t < NBUCK) bucketBase[t] = s[t] - v;        // exclusive
}

__global__ __launch_bounds__(256) void k_csr2(const unsigned int* __restrict__ binP,
                                              const int* __restrict__ tails,
                                              const int* __restrict__ bucketBase,
                                              int* __restrict__ offs,
                                              float* __restrict__ dis,
                                              int* __restrict__ csr) {
    __shared__ unsigned int stage[CAP];
    __shared__ int cnt[512];
    __shared__ int excl[513];
    __shared__ int s[256];
    int b = blockIdx.x;
    int t = threadIdx.x;
    int nodeBase = b << BSH;
    int n = tails[b];
    if (n > CAPB) n = CAPB;
    int base = bucketBase[b];
    const unsigned int* src = binP + (size_t)b * CAPB;

    for (int v = t; v < 512; v += 256) cnt[v] = 0;
    __syncthreads();
    // pass 1: node counts
    for (int i = t; i < n; i += 256)
        atomicAdd(&cnt[src[i] & 511u], 1);
    __syncthreads();
    // pair-scan 512 -> exclusive node offsets (thread t owns elems 2t, 2t+1)
    int v0 = cnt[2 * t], v1 = cnt[2 * t + 1];
    int ps = v0 + v1;
    s[t] = ps;
    __syncthreads();
    for (int off = 1; off < 256; off <<= 1) {
        int tmp = (t >= off) ? s[t - off] : 0;
        __syncthreads();
        s[t] += tmp;
        __syncthreads();
    }
    int ebase = s[t] - ps;
    excl[2 * t]     = ebase;
    excl[2 * t + 1] = ebase + v0;
    if (t == 255) excl[512] = s[255];                // == n
    // offs + dis (coalesced; guard tail bucket)
    {
        int g0 = nodeBase + 2 * t, g1 = g0 + 1;
        if (g0 < N_NODES) { offs[g0] = base + ebase;      dis[g0] = rsqrtf((float)(v0 + 1)); }
        if (g1 < N_NODES) { offs[g1] = base + ebase + v0; dis[g1] = rsqrtf((float)(v1 + 1)); }
        if (b == NBUCK - 1 && t == 0) offs[N_NODES] = base + n;
    }
    // reset cnt for rank pass
    for (int v = t; v < 512; v += 256) cnt[v] = 0;
    __syncthreads();
    // pass 2: counting-sort into LDS stage at exact ranks
    for (int i = t; i < n; i += 256) {
        unsigned int p = src[i];
        int vv  = (int)(p & 511u);
        int row = (int)(p >> BSH);
        int r = excl[vv] + atomicAdd(&cnt[vv], 1);
        if (r < CAP) stage[r] = (unsigned)row;
        else         csr[base + r] = row;            // overflow fallback (rare)
    }
    __syncthreads();
    int lim = n < CAP ? n : CAP;
    for (int i = t; i < lim; i += 256) csr[base + i] = (int)stage[i];
}

// ---------------- GEMM: h16[r] = fp16( dis[r] * (A[r] @ W) ) ----------------

__global__ __launch_bounds__(256) void k_gemm(const float* __restrict__ A,
                                              const float* __restrict__ W,
                                              const float* __restrict__ dis,
                                              uint2* __restrict__ out16) {
    __shared__ float4 xs4[32 * 8];    // 32 rows x 32 k (as float4)
    __shared__ float4 ws4[32 * 32];   // 32 k x 128 cols (as float4)
    int t  = threadIdx.x;
    int tx = t & 31, ty = t >> 5;
    int rb = blockIdx.x * 32;
    const float4* A4 = (const float4*)A;
    const float4* W4 = (const float4*)W;
    float4 acc[4];
#pragma unroll
    for (int i = 0; i < 4; ++i) acc[i] = make_float4(0.f, 0.f, 0.f, 0.f);

    for (int kc = 0; kc < 4; ++kc) {
        {
            int r = t >> 3, c4 = t & 7;
            xs4[r * 8 + c4] = A4[(size_t)(rb + r) * 32 + kc * 8 + c4];
        }
#pragma unroll
        for (int i = 0; i < 4; ++i) {
            int idx = t + i * 256;
            int k = idx >> 5, c4 = idx & 31;
            ws4[k * 32 + c4] = W4[(size_t)(kc * 32 + k) * 32 + c4];
        }
        __syncthreads();
#pragma unroll
        for (int k0 = 0; k0 < 32; k0 += 4) {
            float4 b0 = ws4[(k0 + 0) * 32 + tx];
            float4 b1 = ws4[(k0 + 1) * 32 + tx];
            float4 b2 = ws4[(k0 + 2) * 32 + tx];
            float4 b3 = ws4[(k0 + 3) * 32 + tx];
#pragma unroll
            for (int i = 0; i < 4; ++i) {
                float4 a = xs4[(ty + 8 * i) * 8 + (k0 >> 2)];
                acc[i].x += a.x * b0.x; acc[i].y += a.x * b0.y;
                acc[i].z += a.x * b0.z; acc[i].w += a.x * b0.w;
                acc[i].x += a.y * b1.x; acc[i].y += a.y * b1.y;
                acc[i].z += a.y * b1.z; acc[i].w += a.y * b1.w;
                acc[i].x += a.z * b2.x; acc[i].y += a.z * b2.y;
                acc[i].z += a.z * b2.z; acc[i].w += a.z * b2.w;
                acc[i].x += a.w * b3.x; acc[i].y += a.w * b3.y;
                acc[i].z += a.w * b3.z; acc[i].w += a.w * b3.w;
            }
        }
        __syncthreads();
    }
#pragma unroll
    for (int i = 0; i < 4; ++i) {
        int r = rb + ty + 8 * i;
        float d = dis[r];
        float4 o = acc[i];
        union { __half2 h2[2]; uint2 u; } cvt;
        cvt.h2[0] = __floats2half2_rn(d * o.x, d * o.y);
        cvt.h2[1] = __floats2half2_rn(d * o.z, d * o.w);
        out16[(size_t)r * 32 + tx] = cvt.u;          // 8B/lane, coalesced 256B row
    }
}

// ---------------- aggregation ----------------
// one wave per node; fp16 rows (256B): 32 lanes x uint2(4 halves) cover one
// row, each load instruction fetches TWO neighbor rows (lane half = lane>>5).
// Unroll 8 pairs -> 16 rows in flight. fp32 accumulate; cross-half shfl_xor.

__device__ __forceinline__ float4 h2f4(uint2 p) {
    __half2 a = *reinterpret_cast<__half2*>(&p.x);
    __half2 b = *reinterpret_cast<__half2*>(&p.y);
    float2 fa = __half22float2(a);
    float2 fb = __half22float2(b);
    return make_float4(fa.x, fa.y, fb.x, fb.y);
}

template <bool RELU>
__global__ __launch_bounds__(256) void k_agg(const uint2* __restrict__ h16,
                                             const int* __restrict__ csr,
                                             const int* __restrict__ offs,
                                             const float* __restrict__ dis,
                                             const float* __restrict__ bias,
                                             float* __restrict__ out) {
    int v    = blockIdx.x * 4 + (threadIdx.x >> 6);
    int lane = threadIdx.x & 63;
    int half = lane >> 5;
    int c4   = lane & 31;
    float4 acc = make_float4(0.f, 0.f, 0.f, 0.f);
    if (half == 0) {                                 // self loop term, once
        float4 sv = h2f4(h16[(size_t)v * 32 + c4]);
        acc = sv;
    }
    int s = offs[v], e = offs[v + 1];
    int i = s;
    for (; i + 16 <= e; i += 16) {
        int s0 = csr[i +  0 + half], s1 = csr[i +  2 + half];
        int s2 = csr[i +  4 + half], s3 = csr[i +  6 + half];
        int s4 = csr[i +  8 + half], s5 = csr[i + 10 + half];
        int s6 = csr[i + 12 + half], s7 = csr[i + 14 + half];
        uint2 p0 = h16[(size_t)s0 * 32 + c4];
        uint2 p1 = h16[(size_t)s1 * 32 + c4];
        uint2 p2 = h16[(size_t)s2 * 32 + c4];
        uint2 p3 = h16[(size_t)s3 * 32 + c4];
        uint2 p4 = h16[(size_t)s4 * 32 + c4];
        uint2 p5 = h16[(size_t)s5 * 32 + c4];
        uint2 p6 = h16[(size_t)s6 * 32 + c4];
        uint2 p7 = h16[(size_t)s7 * 32 + c4];
        float4 t0 = h2f4(p0), t1 = h2f4(p1), t2 = h2f4(p2), t3 = h2f4(p3);
        float4 t4 = h2f4(p4), t5 = h2f4(p5), t6 = h2f4(p6), t7 = h2f4(p7);
        acc.x += t0.x; acc.y += t0.y; acc.z += t0.z; acc.w += t0.w;
        acc.x += t1.x; acc.y += t1.y; acc.z += t1.z; acc.w += t1.w;
        acc.x += t2.x; acc.y += t2.y; acc.z += t2.z; acc.w += t2.w;
        acc.x += t3.x; acc.y += t3.y; acc.z += t3.z; acc.w += t3.w;
        acc.x += t4.x; acc.y += t4.y; acc.z += t4.z; acc.w += t4.w;
        acc.x += t5.x; acc.y += t5.y; acc.z += t5.z; acc.w += t5.w;
        acc.x += t6.x; acc.y += t6.y; acc.z += t6.z; acc.w += t6.w;
        acc.x += t7.x; acc.y += t7.y; acc.z += t7.z; acc.w += t7.w;
    }
    for (; i + 2 <= e; i += 2) {
        int s0 = csr[i + half];
        float4 t0 = h2f4(h16[(size_t)s0 * 32 + c4]);
        acc.x += t0.x; acc.y += t0.y; acc.z += t0.z; acc.w += t0.w;
    }
    if (i < e && half == 0) {                        // odd leftover row
        int s0 = csr[i];
        float4 t0 = h2f4(h16[(size_t)s0 * 32 + c4]);
        acc.x += t0.x; acc.y += t0.y; acc.z += t0.z; acc.w += t0.w;
    }
    // reduce the two halves (lane L <-> L+32 hold same features)
    acc.x += __shfl_xor(acc.x, 32, 64);
    acc.y += __shfl_xor(acc.y, 32, 64);
    acc.z += __shfl_xor(acc.z, 32, 64);
    acc.w += __shfl_xor(acc.w, 32, 64);
    if (half == 0) {
        float dv = dis[v];
        float4 bb = ((const float4*)bias)[c4];
        float4 o;
        o.x = dv * acc.x + bb.x;
        o.y = dv * acc.y + bb.y;
        o.z = dv * acc.z + bb.z;
        o.w = dv * acc.w + bb.w;
        if (RELU) {
            o.x = fmaxf(o.x, 0.f); o.y = fmaxf(o.y, 0.f);
            o.z = fmaxf(o.z, 0.f); o.w = fmaxf(o.w, 0.f);
        }
        ((float4*)out)[(size_t)v * 32 + c4] = o;
    }
}

// ---------------- launch ----------------

extern "C" void kernel_launch(void* const* d_in, const int* in_sizes, int n_in,
                              void* d_out, int out_size, void* d_ws, size_t ws_size,
                              hipStream_t stream) {
    const float* x     = (const float*)d_in[0];
    const int*   edges = (const int*)d_in[1];     // harness stages integers as int32
    const float* W1    = (const float*)d_in[2];
    const float* b1    = (const float*)d_in[3];
    const float* W2    = (const float*)d_in[4];
    const float* b2    = (const float*)d_in[5];
    float* out = (float*)d_out;
    const int E = in_sizes[1] / 2;

    // workspace carve (~33 MB)
    char* p = (char*)d_ws;
    auto alloc = [&](size_t bytes) -> char* {
        char* r = p;
        p += (bytes + 255) & ~(size_t)255;
        return r;
    };
    int*   offs       = (int*)alloc((size_t)(N_NODES + 1) * 4);
    float* dis        = (float*)alloc((size_t)N_NODES * 4);
    int*   tails      = (int*)alloc(256 * 4);
    int*   bucketBase = (int*)alloc(256 * 4);
    int*   csr        = (int*)alloc((size_t)E * 4);
    uint2* h16        = (uint2*)alloc((size_t)N_NODES * 128 * 2);   // fp16 h' (25.6MB)
    unsigned int* binP = (unsigned int*)h16;  // alias (12.8MB need): dead before k_gemm

    const int TILES = (E + TILE - 1) / TILE;

    k_init<<<1, 256, 0, stream>>>(tails);
    k_binP<<<TILES, 256, 0, stream>>>(edges, E, tails, binP);
    k_scanB<<<1, 256, 0, stream>>>(tails, bucketBase);
    k_csr2<<<NBUCK, 256, 0, stream>>>(binP, tails, bucketBase, offs, dis, csr);

    // layer 1: h16 = fp16(dis * (x @ W1)) ; aggregate(+b1, relu) -> out (temp)
    k_gemm<<<N_NODES / 32, 256, 0, stream>>>(x, W1, dis, h16);
    k_agg<true><<<N_NODES / 4, 256, 0, stream>>>(h16, csr, offs, dis, b1, out);

    // layer 2: h16 = fp16(dis * (out @ W2)) ; aggregate(+b2) -> out (final)
    k_gemm<<<N_NODES / 32, 256, 0, stream>>>(out, W2, dis, h16);
    k_agg<false><<<N_NODES / 4, 256, 0, stream>>>(h16, csr, offs, dis, b2, out);
}